// Round 6
// baseline (14830.080 us; speedup 1.0000x reference)
//
#include <hip/hip_runtime.h>
#include <hip/hip_bf16.h>

#define EPSF 1e-5f

// ---------------------------------------------------------------------------
// Module-scope scratch. d_out is (2,384,200,200) = 30.72M floats — far too
// small for the intermediates, and d_ws has unknown size, so ALL scratch
// lives here. 51.2M floats = 204.8 MB, lifetime-aliased (map at launch).
// Every region is written before it is read within one launch (idempotent
// across graph replays).
// ---------------------------------------------------------------------------
__device__ float g_arena[51200000];
__device__ float g_stats[768];

// ---------------------------------------------------------------------------
// helpers
// ---------------------------------------------------------------------------
__device__ __forceinline__ float wave_sum(float v) {
#pragma unroll
    for (int o = 32; o > 0; o >>= 1) v += __shfl_down(v, o, 64);
    return v;
}

__device__ __forceinline__ float dot4(float4 a, float4 b) {
    return a.x * b.x + a.y * b.y + a.z * b.z + a.w * b.w;
}

__device__ __forceinline__ unsigned short bfbits(float x) {
    __hip_bfloat16 h = __float2bfloat16(x);
    return *reinterpret_cast<unsigned short*>(&h);
}

__device__ __forceinline__ float to_f(float x) { return x; }
__device__ __forceinline__ float to_f(__hip_bfloat16 x) { return __bfloat162float(x); }

__device__ __forceinline__ void store4(float* p, float4 r) { *(float4*)p = r; }
__device__ __forceinline__ void store4(__hip_bfloat16* p, float4 r) {
    ushort4 u = make_ushort4(bfbits(r.x), bfbits(r.y), bfbits(r.z), bfbits(r.w));
    *reinterpret_cast<ushort4*>(p) = u;
}

// ---------------------------------------------------------------------------
// zero_stats
// ---------------------------------------------------------------------------
__global__ void zero_stats_kernel() {
    int i = blockIdx.x * 256 + threadIdx.x;
    if (i < 768) g_stats[i] = 0.f;
}

// ---------------------------------------------------------------------------
// gemm128: out[p][ocb+oc] = sum_c A[p][c] * W[ocb+oc][c]  (+bias,+resid,relu)
// A layout: seq [p][Cin] (feat_mode=0) or NCHW feat [b][Cin][40000] (feat_mode=1)
// tile: 64 positions x 128 out-channels, 256 threads, thread = 4 oc x 8 pos
// ---------------------------------------------------------------------------
template <typename TIN, typename TOUT>
__global__ __launch_bounds__(256) void gemm128_kernel(
    const TIN* __restrict__ A, const float* __restrict__ W,
    const float* __restrict__ bias, const float* __restrict__ resid,
    TOUT* __restrict__ out, int Cin, int Nout, int feat_mode, int relu_flag)
{
    __shared__ float sa[16][68];
    __shared__ float sw[16][132];

    const int tid = threadIdx.x;
    const int p0 = blockIdx.x * 64;
    const int ocb = blockIdx.y * 128;
    const int oc_g = tid & 31;
    const int pos_g = tid >> 5;
    const int oc0 = oc_g * 4;
    const int pp0 = pos_g * 8;

    float acc[4][8];
#pragma unroll
    for (int a = 0; a < 4; a++)
#pragma unroll
        for (int j = 0; j < 8; j++) acc[a][j] = 0.f;

    const int bb = p0 / 40000;
    const int hw0 = p0 % 40000;

    for (int cb = 0; cb < Cin; cb += 16) {
        __syncthreads();
        if (feat_mode) {
#pragma unroll
            for (int i = 0; i < 4; i++) {
                int e = tid + i * 256;
                int cc = e >> 6, pos = e & 63;
                sa[cc][pos] = to_f(A[((size_t)bb * Cin + cb + cc) * 40000 + hw0 + pos]);
            }
        } else {
#pragma unroll
            for (int i = 0; i < 4; i++) {
                int e = tid + i * 256;
                int pos = e >> 4, cc = e & 15;
                sa[cc][pos] = to_f(A[(size_t)(p0 + pos) * Cin + cb + cc]);
            }
        }
#pragma unroll
        for (int i = 0; i < 8; i++) {
            int e = tid + i * 256;
            int oc = e >> 4, cc = e & 15;
            sw[cc][oc] = W[(size_t)(ocb + oc) * Cin + cb + cc];
        }
        __syncthreads();
#pragma unroll
        for (int cc = 0; cc < 16; cc++) {
            float4 wv = *(const float4*)&sw[cc][oc0];
            float4 a0 = *(const float4*)&sa[cc][pp0];
            float4 a1 = *(const float4*)&sa[cc][pp0 + 4];
            float av[8] = {a0.x, a0.y, a0.z, a0.w, a1.x, a1.y, a1.z, a1.w};
            float wr[4] = {wv.x, wv.y, wv.z, wv.w};
#pragma unroll
            for (int jj = 0; jj < 4; jj++)
#pragma unroll
                for (int j = 0; j < 8; j++)
                    acc[jj][j] += wr[jj] * av[j];
        }
    }

    float bv[4] = {0.f, 0.f, 0.f, 0.f};
    if (bias) {
#pragma unroll
        for (int jj = 0; jj < 4; jj++) bv[jj] = bias[ocb + oc0 + jj];
    }
#pragma unroll
    for (int j = 0; j < 8; j++) {
        size_t row = (size_t)(p0 + pp0 + j) * Nout + ocb + oc0;
        float4 r;
        r.x = acc[0][j] + bv[0];
        r.y = acc[1][j] + bv[1];
        r.z = acc[2][j] + bv[2];
        r.w = acc[3][j] + bv[3];
        if (resid) {
            float4 rr = *(const float4*)&resid[row];
            r.x += rr.x; r.y += rr.y; r.z += rr.z; r.w += rr.w;
        }
        if (relu_flag) {
            r.x = fmaxf(r.x, 0.f); r.y = fmaxf(r.y, 0.f);
            r.z = fmaxf(r.z, 0.f); r.w = fmaxf(r.w, 0.f);
        }
        store4(&out[row], r);
    }
}

// ---------------------------------------------------------------------------
// score: h = relu(si @ W1^T + b1) (64), score = h @ w2 + b2
// ---------------------------------------------------------------------------
__global__ __launch_bounds__(256) void score_kernel(
    const float* __restrict__ rad_seq, const float* __restrict__ img_seq,
    const float* __restrict__ w1, const float* __restrict__ b1,
    const float* __restrict__ w2, const float* __restrict__ b2,
    float* __restrict__ score)
{
    __shared__ float sw1[64][20];
    __shared__ float ss[16][20];
    const int tid = threadIdx.x;
    const int p0 = blockIdx.x * 16;
    const int wvid = tid >> 6;
    const int l = tid & 63;
    float acc[4] = {0.f, 0.f, 0.f, 0.f};

    for (int cb = 0; cb < 256; cb += 16) {
        __syncthreads();
#pragma unroll
        for (int i = 0; i < 4; i++) {
            int e = tid + i * 256;
            int ll = e >> 4, cc = e & 15;
            sw1[ll][cc] = w1[(size_t)ll * 256 + cb + cc];
        }
        {
            int pos = tid >> 4, cc = tid & 15;
            int c = cb + cc;
            ss[pos][cc] = (c < 128)
                ? rad_seq[(size_t)(p0 + pos) * 128 + c]
                : img_seq[(size_t)(p0 + pos) * 128 + (c - 128)];
        }
        __syncthreads();
#pragma unroll
        for (int c4 = 0; c4 < 4; c4++) {
            float4 wv = *(const float4*)&sw1[l][c4 * 4];
#pragma unroll
            for (int j = 0; j < 4; j++) {
                float4 sv = *(const float4*)&ss[wvid * 4 + j][c4 * 4];
                acc[j] += dot4(wv, sv);
            }
        }
    }
    float b1v = b1[l], w2v = w2[l], b2v = b2[0];
#pragma unroll
    for (int j = 0; j < 4; j++) {
        float h = fmaxf(acc[j] + b1v, 0.f);
        float v = wave_sum(h * w2v);
        if (l == 0) score[p0 + wvid * 4 + j] = v + b2v;
    }
}

// ---------------------------------------------------------------------------
// topk: exact stable rank selection (matches jax.lax.top_k tie-breaking)
// ---------------------------------------------------------------------------
__global__ __launch_bounds__(256) void topk_kernel(
    const float* __restrict__ score, int* __restrict__ idx)
{
    __shared__ float s[200];
    const int n = blockIdx.x;
    const int t = threadIdx.x;
    if (t < 200) s[t] = score[(size_t)n * 200 + t];
    __syncthreads();
    if (t < 200) {
        float my = s[t];
        int cnt = 0;
        for (int j = 0; j < 200; j++) {
            float o = s[j];
            cnt += (o > my) || (o == my && j < t);
        }
        if (cnt < 100) idx[n * 100 + cnt] = t;
    }
}

// ---------------------------------------------------------------------------
// ln_gather: out[r][:] = LN(in[src_row][:]) * g + b  over 128 channels
// ---------------------------------------------------------------------------
__global__ __launch_bounds__(256) void ln_gather_kernel(
    const float* __restrict__ in, const int* __restrict__ gidx,
    const float* __restrict__ g, const float* __restrict__ bb,
    float* __restrict__ out)
{
    __shared__ float red[4];
    const int tid = threadIdx.x;
    const int grp = tid >> 7;
    const int t = tid & 127;
    const int r = blockIdx.x * 2 + grp;

    size_t src_row;
    if (gidx) src_row = (size_t)(r / 100) * 200 + gidx[r];
    else      src_row = (size_t)r;

    float x = in[src_row * 128 + t];
    float s = wave_sum(x);
    if ((tid & 63) == 0) red[tid >> 6] = s;
    __syncthreads();
    float m = (red[grp * 2] + red[grp * 2 + 1]) * 0.0078125f;
    float d = x - m;
    float s2 = wave_sum(d * d);
    __syncthreads();
    if ((tid & 63) == 0) red[tid >> 6] = s2;
    __syncthreads();
    float var = (red[grp * 2] + red[grp * 2 + 1]) * 0.0078125f;
    out[(size_t)r * 128 + t] = d * rsqrtf(var + EPSF) * g[t] + bb[t];
}

// ---------------------------------------------------------------------------
// attention: block = (head h, row n); thread = one query w (<200)
// ---------------------------------------------------------------------------
__global__ __launch_bounds__(256) void attention_kernel(
    const float* __restrict__ qh, const float* __restrict__ kh,
    const float* __restrict__ vh, float* __restrict__ o)
{
    __shared__ float sk[100][16];
    __shared__ float sv[100][16];
    const int h = blockIdx.x;
    const int n = blockIdx.y;
    const int tid = threadIdx.x;

    for (int e = tid; e < 1600; e += 256) {
        int kk = e >> 4, d = e & 15;
        size_t src = ((size_t)n * 100 + kk) * 128 + h * 16 + d;
        sk[kk][d] = kh[src];
        sv[kk][d] = vh[src];
    }
    __syncthreads();

    if (tid < 200) {
        const float* qp = &qh[((size_t)n * 200 + tid) * 128 + h * 16];
        float4 q0 = *(const float4*)(qp + 0);
        float4 q1 = *(const float4*)(qp + 4);
        float4 q2 = *(const float4*)(qp + 8);
        float4 q3 = *(const float4*)(qp + 12);

        float m = -INFINITY, l = 0.f;
        float4 a0 = {0,0,0,0}, a1 = {0,0,0,0}, a2 = {0,0,0,0}, a3 = {0,0,0,0};

        for (int kk = 0; kk < 100; kk++) {
            const float4* kp = (const float4*)&sk[kk][0];
            float s = dot4(q0, kp[0]) + dot4(q1, kp[1]) +
                      dot4(q2, kp[2]) + dot4(q3, kp[3]);
            s *= 0.25f;
            float nm = fmaxf(m, s);
            float corr = __expf(m - nm);
            float pe = __expf(s - nm);
            l = l * corr + pe;
            const float4* vp = (const float4*)&sv[kk][0];
            float4 v0 = vp[0], v1 = vp[1], v2 = vp[2], v3 = vp[3];
            a0.x = a0.x * corr + pe * v0.x; a0.y = a0.y * corr + pe * v0.y;
            a0.z = a0.z * corr + pe * v0.z; a0.w = a0.w * corr + pe * v0.w;
            a1.x = a1.x * corr + pe * v1.x; a1.y = a1.y * corr + pe * v1.y;
            a1.z = a1.z * corr + pe * v1.z; a1.w = a1.w * corr + pe * v1.w;
            a2.x = a2.x * corr + pe * v2.x; a2.y = a2.y * corr + pe * v2.y;
            a2.z = a2.z * corr + pe * v2.z; a2.w = a2.w * corr + pe * v2.w;
            a3.x = a3.x * corr + pe * v3.x; a3.y = a3.y * corr + pe * v3.y;
            a3.z = a3.z * corr + pe * v3.z; a3.w = a3.w * corr + pe * v3.w;
            m = nm;
        }
        float inv = 1.f / l;
        float* op = &o[((size_t)n * 200 + tid) * 128 + h * 16];
        a0.x *= inv; a0.y *= inv; a0.z *= inv; a0.w *= inv;
        a1.x *= inv; a1.y *= inv; a1.z *= inv; a1.w *= inv;
        a2.x *= inv; a2.y *= inv; a2.z *= inv; a2.w *= inv;
        a3.x *= inv; a3.y *= inv; a3.z *= inv; a3.w *= inv;
        *(float4*)(op + 0)  = a0;
        *(float4*)(op + 4)  = a1;
        *(float4*)(op + 8)  = a2;
        *(float4*)(op + 12) = a3;
    }
}

// ---------------------------------------------------------------------------
// enhance: delta = x @ Wd^T; gate = sigmoid((radar,image) @ Wg^T + gb) * rmask
// rad_e = radar + gamma*gate*rmask*delta   (d_in untouched)
// ---------------------------------------------------------------------------
__global__ __launch_bounds__(256) void enhance_kernel(
    const float* __restrict__ x, const float* __restrict__ radar,
    const float* __restrict__ image, const float* __restrict__ wd,
    const float* __restrict__ wg, const float* __restrict__ gb,
    const float* __restrict__ gamma_p, float* __restrict__ rad_e)
{
    __shared__ float sa[16][68];
    __shared__ float sw[16][132];
    const int tid = threadIdx.x;
    const int b = blockIdx.y;
    const int hw0 = blockIdx.x * 64;
    const int p0 = b * 40000 + hw0;
    const int oc_g = tid & 31, pos_g = tid >> 5;
    const int oc0 = oc_g * 4, pp0 = pos_g * 8;

    float accd[4][8] = {};
    float accg[4][8] = {};

    // phase 1: delta over x [p][128]
    for (int cb = 0; cb < 128; cb += 16) {
        __syncthreads();
#pragma unroll
        for (int i = 0; i < 4; i++) {
            int e = tid + i * 256;
            int pos = e >> 4, cc = e & 15;
            sa[cc][pos] = x[(size_t)(p0 + pos) * 128 + cb + cc];
        }
#pragma unroll
        for (int i = 0; i < 8; i++) {
            int e = tid + i * 256;
            int oc = e >> 4, cc = e & 15;
            sw[cc][oc] = wd[(size_t)oc * 128 + cb + cc];
        }
        __syncthreads();
#pragma unroll
        for (int cc = 0; cc < 16; cc++) {
            float4 wv = *(const float4*)&sw[cc][oc0];
            float4 b0 = *(const float4*)&sa[cc][pp0];
            float4 b1 = *(const float4*)&sa[cc][pp0 + 4];
            float av[8] = {b0.x, b0.y, b0.z, b0.w, b1.x, b1.y, b1.z, b1.w};
            float wr[4] = {wv.x, wv.y, wv.z, wv.w};
#pragma unroll
            for (int jj = 0; jj < 4; jj++)
#pragma unroll
                for (int j = 0; j < 8; j++)
                    accd[jj][j] += wr[jj] * av[j];
        }
    }
    // phase 2: gate over concat(radar, image) NCHW feat, Cin=384
    for (int cb = 0; cb < 384; cb += 16) {
        __syncthreads();
        const float* src = (cb < 128)
            ? radar + ((size_t)b * 128 + cb) * 40000
            : image + ((size_t)b * 256 + (cb - 128)) * 40000;
#pragma unroll
        for (int i = 0; i < 4; i++) {
            int e = tid + i * 256;
            int cc = e >> 6, pos = e & 63;
            sa[cc][pos] = src[(size_t)cc * 40000 + hw0 + pos];
        }
#pragma unroll
        for (int i = 0; i < 8; i++) {
            int e = tid + i * 256;
            int oc = e >> 4, cc = e & 15;
            sw[cc][oc] = wg[(size_t)oc * 384 + cb + cc];
        }
        __syncthreads();
#pragma unroll
        for (int cc = 0; cc < 16; cc++) {
            float4 wv = *(const float4*)&sw[cc][oc0];
            float4 b0 = *(const float4*)&sa[cc][pp0];
            float4 b1 = *(const float4*)&sa[cc][pp0 + 4];
            float av[8] = {b0.x, b0.y, b0.z, b0.w, b1.x, b1.y, b1.z, b1.w};
            float wr[4] = {wv.x, wv.y, wv.z, wv.w};
#pragma unroll
            for (int jj = 0; jj < 4; jj++)
#pragma unroll
                for (int j = 0; j < 8; j++)
                    accg[jj][j] += wr[jj] * av[j];
        }
    }

    const float gmm = gamma_p[0];
#pragma unroll
    for (int jj = 0; jj < 4; jj++) {
        int oc = oc0 + jj;
        float gbv = gb[oc];
#pragma unroll
        for (int j = 0; j < 8; j++) {
            int hw = hw0 + pp0 + j;
            int hrow = hw / 200;
            float rm = fmaxf(0.3f, 1.0f - 0.7f * ((float)hrow * (1.0f / 199.0f)));
            float gsig = 1.f / (1.f + __expf(-(accg[jj][j] + gbv)));
            size_t ridx = ((size_t)b * 128 + oc) * 40000 + hw;
            rad_e[ridx] = radar[ridx] + gmm * gsig * rm * accd[jj][j];
        }
    }
}

// ---------------------------------------------------------------------------
// conv3x3: 384->384 SAME, fp32; ch 0..127 = rad_e (arena), 128..383 = image.
// Accumulates per-channel sum/sumsq into g_stats.
// ---------------------------------------------------------------------------
__global__ __launch_bounds__(256) void conv3x3_kernel(
    const float* __restrict__ rad_e, const float* __restrict__ image,
    const float* __restrict__ Wc, float* __restrict__ out)
{
    __shared__ float sa[8][3][52];
    __shared__ float sw[128 * 73];

    const int tid = threadIdx.x;
    const int xt = blockIdx.x;
    const int y = blockIdx.y;
    const int b = blockIdx.z / 3;
    const int ocg = blockIdx.z % 3;
    const int oc = tid & 127;
    const int half = tid >> 7;
    const int x0 = xt * 50;
    const int xbase = half * 25;

    float acc[25];
#pragma unroll
    for (int i = 0; i < 25; i++) acc[i] = 0.f;

    for (int icb = 0; icb < 384; icb += 8) {
        __syncthreads();
        for (int e = tid; e < 1248; e += 256) {
            int ic = e / 156;
            int rr = e - ic * 156;
            int row = rr / 52;
            int col = rr - row * 52;
            int yy = y + row - 1;
            int xx = x0 + col - 1;
            float v = 0.f;
            if (yy >= 0 && yy < 200 && xx >= 0 && xx < 200) {
                int icg = icb + ic;
                v = (icg < 128)
                    ? rad_e[((size_t)(b * 128 + icg) * 200 + yy) * 200 + xx]
                    : image[((size_t)(b * 256 + (icg - 128)) * 200 + yy) * 200 + xx];
            }
            sa[ic][row][col] = v;
        }
        for (int e = tid; e < 9216; e += 256) {
            int o = e / 72;
            int rr = e - o * 72;
            sw[o * 73 + rr] = Wc[(size_t)(ocg * 128 + o) * 3456 + icb * 9 + rr];
        }
        __syncthreads();
#pragma unroll
        for (int ic = 0; ic < 8; ic++) {
#pragma unroll
            for (int dy = 0; dy < 3; dy++) {
                float rv[27];
#pragma unroll
                for (int k = 0; k < 27; k++) rv[k] = sa[ic][dy][xbase + k];
#pragma unroll
                for (int dx = 0; dx < 3; dx++) {
                    float w = sw[oc * 73 + ic * 9 + dy * 3 + dx];
#pragma unroll
                    for (int i = 0; i < 25; i++) acc[i] += rv[i + dx] * w;
                }
            }
        }
    }

    float s1 = 0.f, s2 = 0.f;
    size_t ob = ((size_t)(b * 384 + ocg * 128 + oc) * 200 + y) * 200 + x0 + xbase;
#pragma unroll
    for (int i = 0; i < 25; i++) {
        out[ob + i] = acc[i];
        s1 += acc[i];
        s2 += acc[i] * acc[i];
    }
    atomicAdd(&g_stats[(ocg * 128 + oc) * 2], s1);
    atomicAdd(&g_stats[(ocg * 128 + oc) * 2 + 1], s2);
}

// ---------------------------------------------------------------------------
// bn_relu: in-place on d_out (30,720,000 floats = 7,680,000 float4)
// ---------------------------------------------------------------------------
__global__ __launch_bounds__(256) void bn_relu_kernel(
    float* __restrict__ out, const float* __restrict__ g,
    const float* __restrict__ bb)
{
    int i = blockIdx.x * 256 + threadIdx.x;   // float4 index < 7,680,000
    int flat = i * 4;
    int oc = (flat / 40000) % 384;
    float m = g_stats[oc * 2] * (1.f / 80000.f);
    float v = g_stats[oc * 2 + 1] * (1.f / 80000.f) - m * m;
    float inv = rsqrtf(v + EPSF);
    float sc = g[oc] * inv;
    float sh = bb[oc] - m * sc;
    float4 c = ((float4*)out)[i];
    c.x = fmaxf(c.x * sc + sh, 0.f);
    c.y = fmaxf(c.y * sc + sh, 0.f);
    c.z = fmaxf(c.z * sc + sh, 0.f);
    c.w = fmaxf(c.w * sc + sh, 0.f);
    ((float4*)out)[i] = c;
}

// ---------------------------------------------------------------------------
// launch. g_arena element-offset lifetime map (51.2M floats):
//   [       0,10240000) img_seq (proj..ln_gather kv)   } then hbuf
//   [10240000,20480000) rad_seq (proj..out-proj resid) } (bf16 80000x512)
//   [20480000,30720000) score+idx -> qh -> x
//   [30720000,35840000) kh
//   [35840000,40960000) vh
//   [40960000,51200000) fbuf: kvn -> qn -> o -> xn ; then rad_e
// d_out is written ONLY by conv + bn_relu. d_ws unused. d_in never written.
// ---------------------------------------------------------------------------
extern "C" void kernel_launch(void* const* d_in, const int* in_sizes, int n_in,
                              void* d_out, int out_size, void* d_ws, size_t ws_size,
                              hipStream_t stream)
{
    (void)in_sizes; (void)n_in; (void)out_size; (void)d_ws; (void)ws_size;

    const float* radar      = (const float*)d_in[0];
    const float* image      = (const float*)d_in[1];
    const float* img_proj_w = (const float*)d_in[2];
    const float* rad_proj_w = (const float*)d_in[3];
    const float* in_proj_w  = (const float*)d_in[4];
    const float* in_proj_b  = (const float*)d_in[5];
    const float* out_proj_w = (const float*)d_in[6];
    const float* out_proj_b = (const float*)d_in[7];
    const float* ln1q_g     = (const float*)d_in[8];
    const float* ln1q_b     = (const float*)d_in[9];
    const float* ln1kv_g    = (const float*)d_in[10];
    const float* ln1kv_b    = (const float*)d_in[11];
    const float* ln2_g      = (const float*)d_in[12];
    const float* ln2_b      = (const float*)d_in[13];
    const float* ffn_w1     = (const float*)d_in[14];
    const float* ffn_b1     = (const float*)d_in[15];
    const float* ffn_w2     = (const float*)d_in[16];
    const float* ffn_b2     = (const float*)d_in[17];
    const float* score_w1   = (const float*)d_in[18];
    const float* score_b1   = (const float*)d_in[19];
    const float* score_w2   = (const float*)d_in[20];
    const float* score_b2   = (const float*)d_in[21];
    const float* rad_delta_w= (const float*)d_in[22];
    const float* gamma      = (const float*)d_in[23];
    const float* gate_w     = (const float*)d_in[24];
    const float* gate_b     = (const float*)d_in[25];
    const float* fuse_w     = (const float*)d_in[26];
    const float* bn_g       = (const float*)d_in[27];
    const float* bn_b       = (const float*)d_in[28];

    float* arena = nullptr;
    hipGetSymbolAddress((void**)&arena, HIP_SYMBOL(g_arena));

    float* img_seq = arena;                    // 80000x128
    float* rad_seq = arena + 10240000;         // 80000x128
    float* score   = arena + 20480000;         // 80000
    int*   idx     = (int*)(arena + 20560000); // 40000 ints
    float* qh      = arena + 20480000;         // overlays score/idx (dead)
    float* xbuf    = arena + 20480000;         // overlays qh (dead after attn)
    float* kh      = arena + 30720000;         // 40000x128
    float* vh      = arena + 35840000;         // 40000x128
    float* fbuf    = arena + 40960000;         // kvn/qn/o/xn (<=80000x128)
    float* rad_e   = arena + 40960000;         // overlays fbuf (dead after FFN1)
    __hip_bfloat16* hbuf = (__hip_bfloat16*)arena; // 80000x512 bf16 over dead A+B

    const dim3 blk(256);

    // projections: NCHW -> seq [p][128]
    gemm128_kernel<float, float><<<dim3(1250, 1), blk, 0, stream>>>(
        image, img_proj_w, nullptr, nullptr, img_seq, 256, 128, 1, 0);
    gemm128_kernel<float, float><<<dim3(1250, 1), blk, 0, stream>>>(
        radar, rad_proj_w, nullptr, nullptr, rad_seq, 128, 128, 1, 0);

    // scoring MLP + top-k
    score_kernel<<<dim3(5000), blk, 0, stream>>>(
        rad_seq, img_seq, score_w1, score_b1, score_w2, score_b2, score);
    topk_kernel<<<dim3(400), blk, 0, stream>>>(score, idx);

    // gathered LN(kv) -> kvn (fbuf), then K/V projections
    ln_gather_kernel<<<dim3(20000), blk, 0, stream>>>(
        img_seq, idx, ln1kv_g, ln1kv_b, fbuf);
    gemm128_kernel<float, float><<<dim3(625, 1), blk, 0, stream>>>(
        fbuf, in_proj_w + 128 * 128, in_proj_b + 128, nullptr, kh, 128, 128, 0, 0);
    gemm128_kernel<float, float><<<dim3(625, 1), blk, 0, stream>>>(
        fbuf, in_proj_w + 256 * 128, in_proj_b + 256, nullptr, vh, 128, 128, 0, 0);

    // LN(q) -> qn (fbuf, overlays dead kvn), Q projection -> qh
    ln_gather_kernel<<<dim3(40000), blk, 0, stream>>>(
        rad_seq, nullptr, ln1q_g, ln1q_b, fbuf);
    gemm128_kernel<float, float><<<dim3(1250, 1), blk, 0, stream>>>(
        fbuf, in_proj_w, in_proj_b, nullptr, qh, 128, 128, 0, 0);

    // attention -> o (fbuf, overlays dead qn)
    attention_kernel<<<dim3(8, 400), blk, 0, stream>>>(qh, kh, vh, fbuf);

    // out-proj + residual -> x (overlays dead qh)
    gemm128_kernel<float, float><<<dim3(1250, 1), blk, 0, stream>>>(
        fbuf, out_proj_w, out_proj_b, rad_seq, xbuf, 128, 128, 0, 0);

    // FFN: xn = ln2(x) -> fbuf; h = relu(xn@W1^T+b1) -> hbuf (bf16);
    // x += h@W2^T+b2 (in place, same-thread read-then-write)
    ln_gather_kernel<<<dim3(40000), blk, 0, stream>>>(
        xbuf, nullptr, ln2_g, ln2_b, fbuf);
    gemm128_kernel<float, __hip_bfloat16><<<dim3(1250, 4), blk, 0, stream>>>(
        fbuf, ffn_w1, ffn_b1, nullptr, hbuf, 128, 512, 0, 1);
    gemm128_kernel<__hip_bfloat16, float><<<dim3(1250, 1), blk, 0, stream>>>(
        hbuf, ffn_w2, ffn_b2, xbuf, xbuf, 512, 128, 0, 0);

    // enhance: rad_e = radar + gamma*gate*rmask*delta (overlays dead xn)
    enhance_kernel<<<dim3(625, 2), blk, 0, stream>>>(
        xbuf, radar, image, rad_delta_w, gate_w, gate_b, gamma, rad_e);

    // zero stats, conv 3x3 -> d_out, batch-norm+relu in place
    zero_stats_kernel<<<dim3(3), blk, 0, stream>>>();
    conv3x3_kernel<<<dim3(4, 200, 6), blk, 0, stream>>>(
        rad_e, image, fuse_w, (float*)d_out);
    bn_relu_kernel<<<dim3(30000), blk, 0, stream>>>(
        (float*)d_out, bn_g, bn_b);
}